// Round 8
// baseline (194.787 us; speedup 1.0000x reference)
//
#include <hip/hip_runtime.h>
#include <stdint.h>

// ---------------------------------------------------------------------------
// MultiHeadAttention forward, MI355X/gfx950.  Round 8.
// fp32 I/O, bf16 MFMA compute. B=2 S=2048 D=1024 H=16 HD=64. M=4096.
// R8 vs R7 (passed, 190.8 us; attn 59.2):
//  1) attn: uniform-work blocks. Grid (8,16,2): block x handles q-tiles
//     {x, 15-x} SEQUENTIALLY -> every block does exactly 17 K-tile iters.
//     R7's pairing balanced totals but the short block exited early, leaving
//     the CU at 4 waves for most of the dispatch (Occupancy 12.6%). Now all
//     256 blocks are identical: no tail, no stagger.
//  2) cvt_x + cvt_w3 merged into one launch (one fewer dispatch gap).
// Pipeline: cvt_all(x,Wq,Wk,Wv -> d_out scratch bf16) -> gemm_qkv_a -> attn
//        -> cvt Wo (-> ws@Qw, Q dead) -> gemm_out_a (fp32 out over d_out).
// MFMA mfma_f32_16x16x32_bf16 layouts [m89-verified]:
//   A-frag: lane(quad,l15) holds A[m=l15][k=quad*8+j]  (contig bf16x8)
//   B-frag: B[n=l15][k=quad*8+j];  C/D: col=l15, row=quad*4+reg
// Async staging swizzle: LDS[r][pc] = G[r][pc^(r&7)]; frag reads ck^(r&7).
// ---------------------------------------------------------------------------

typedef __bf16 bf16_t;
typedef __bf16 bf16x8 __attribute__((ext_vector_type(8)));
typedef float  f32x4  __attribute__((ext_vector_type(4)));
typedef uint32_t u32x4 __attribute__((ext_vector_type(4)));

#define MFMA16(A, B, C) __builtin_amdgcn_mfma_f32_16x16x32_bf16(A, B, C, 0, 0, 0)

__device__ __forceinline__ void async_ld16(const bf16_t* g, bf16_t* l) {
  __builtin_amdgcn_global_load_lds(
      (const __attribute__((address_space(1))) void*)g,
      (__attribute__((address_space(3))) void*)l, 16, 0, 0);
}

// --- fp32 -> bf16 converters -----------------------------------------------
__device__ __forceinline__ void cvt4(const float* s, bf16_t* d, int i4) {
  const float4 v = *(const float4*)(s + i4);
  union { uint64_t u; bf16_t h[4]; } pk;
  pk.h[0] = (bf16_t)v.x; pk.h[1] = (bf16_t)v.y;
  pk.h[2] = (bf16_t)v.z; pk.h[3] = (bf16_t)v.w;
  *(uint64_t*)(d + i4) = pk.u;
}

// y=0: x (4096 blocks); y=1..3: Wq/Wk/Wv (first 1024 blocks each).
__global__ __launch_bounds__(256) void cvt_all(
    const float* __restrict__ sx, const float* __restrict__ s1,
    const float* __restrict__ s2, const float* __restrict__ s3,
    bf16_t* __restrict__ dx, bf16_t* __restrict__ d1,
    bf16_t* __restrict__ d2, bf16_t* __restrict__ d3) {
  const int y = blockIdx.y;
  if (y != 0 && blockIdx.x >= 1024) return;
  const int i4 = (blockIdx.x * 256 + threadIdx.x) * 4;
  const float* s = (y == 0) ? sx : (y == 1) ? s1 : (y == 2) ? s2 : s3;
  bf16_t*      d = (y == 0) ? dx : (y == 1) ? d1 : (y == 2) ? d2 : d3;
  cvt4(s, d, i4);
}

__global__ __launch_bounds__(256) void cvt_one(const float* __restrict__ s,
                                               bf16_t* __restrict__ d) {
  cvt4(s, d, (blockIdx.x * 256 + threadIdx.x) * 4);
}

// ---------------------------------------------------------------------------
// Async-staged bf16 GEMM core (m97 structure): global_load_lds width=16,
// XOR swizzle on the global source chunk, unpadded LDS (128x64).
// D[m,n] = sum_k A[m,k]*W[n,k];  A: 4096x1024, W: 1024x1024, both bf16.
// mode 0: Q/K [B,H,S,64]; mode 1: V^T [B,H,64,S]; mode 2: row-major FP32+bias.
// ---------------------------------------------------------------------------
__device__ __forceinline__ void gemm_core_async(const bf16_t* __restrict__ A,
                                                const bf16_t* __restrict__ W,
                                                bf16_t* __restrict__ D,
                                                float* __restrict__ Dout,
                                                const float* __restrict__ bias,
                                                int mode) {
  __shared__ __align__(16) bf16_t As[128 * 64];
  __shared__ __align__(16) bf16_t Bs[128 * 64];

  const int tid  = threadIdx.x;
  const int lane = tid & 63;
  const int w    = tid >> 6;
  const int quad = lane >> 4;
  const int l15  = lane & 15;
  const int bm   = blockIdx.y * 128;
  const int bn   = blockIdx.x * 128;
  const int wm   = (w >> 1) * 64;
  const int wn   = (w & 1) * 64;
  const int sr   = lane >> 3;       // row within 8-row group
  const int sc   = lane & 7;        // physical 16B chunk

  f32x4 acc[4][4] = {};

  for (int k0 = 0; k0 < 1024; k0 += 64) {
#pragma unroll
    for (int j = 0; j < 4; ++j) {
      const int r0 = w * 32 + j * 8;               // wave-uniform LDS base row
      const int r  = r0 + sr;
      const int c  = sc ^ (r & 7);                 // swizzled global chunk
      async_ld16(A + (size_t)(bm + r) * 1024 + k0 + c * 8, &As[r0 * 64]);
      async_ld16(W + (size_t)(bn + r) * 1024 + k0 + c * 8, &Bs[r0 * 64]);
    }
    __syncthreads();    // drains vmcnt -> staged data visible
#pragma unroll
    for (int kk = 0; kk < 64; kk += 32) {
      const int ck = (kk >> 3) + quad;             // logical chunk
      bf16x8 aF[4], bF[4];
#pragma unroll
      for (int mt = 0; mt < 4; ++mt) {
        const int r = wm + mt * 16 + l15;
        aF[mt] = *(const bf16x8*)&As[r * 64 + (ck ^ (r & 7)) * 8];
      }
#pragma unroll
      for (int nt = 0; nt < 4; ++nt) {
        const int r = wn + nt * 16 + l15;
        bF[nt] = *(const bf16x8*)&Bs[r * 64 + (ck ^ (r & 7)) * 8];
      }
#pragma unroll
      for (int mt = 0; mt < 4; ++mt)
#pragma unroll
        for (int nt = 0; nt < 4; ++nt)
          acc[mt][nt] = MFMA16(aF[mt], bF[nt], acc[mt][nt]);
    }
    __syncthreads();    // all reads done before next staging overwrites
  }

  // Epilogue. C/D: col = l15, row = quad*4 + reg.
#pragma unroll
  for (int mt = 0; mt < 4; ++mt) {
#pragma unroll
    for (int nt = 0; nt < 4; ++nt) {
      const int n  = bn + wn + nt * 16 + l15;
      const int mb = bm + wm + mt * 16 + quad * 4;
      if (mode == 0) {               // Q/K: [B,H,S,64]
        const int h = n >> 6, hd = n & 63;
#pragma unroll
        for (int r = 0; r < 4; ++r) {
          const int m = mb + r;
          const int b = m >> 11, s = m & 2047;
          D[(size_t)b * 2097152 + (size_t)h * 131072 + (size_t)s * 64 + hd] =
              (bf16_t)acc[mt][nt][r];
        }
      } else if (mode == 1) {        // V^T: [B,H,64,S]; 4 consecutive tokens
        const int h = n >> 6, hd = n & 63;
        const int b = mb >> 11, s0 = mb & 2047;
        union { uint64_t u; bf16_t h4[4]; } pk;
#pragma unroll
        for (int r = 0; r < 4; ++r) pk.h4[r] = (bf16_t)acc[mt][nt][r];
        *(uint64_t*)(D + (size_t)b * 2097152 + (size_t)h * 131072 +
                     (size_t)hd * 2048 + s0) = pk.u;
      } else {                       // out: row-major FP32 + fp32 bias
        const float bv = bias[n];
#pragma unroll
        for (int r = 0; r < 4; ++r) {
          const int m = mb + r;
          Dout[(size_t)m * 1024 + n] = acc[mt][nt][r] + bv;
        }
      }
    }
  }
}

__global__ __launch_bounds__(256, 2) void gemm_qkv_a(
    const bf16_t* __restrict__ X,  const bf16_t* __restrict__ Wq,
    const bf16_t* __restrict__ Wk, const bf16_t* __restrict__ Wv,
    bf16_t* __restrict__ Q, bf16_t* __restrict__ K, bf16_t* __restrict__ V) {
  const int z = blockIdx.z;
  const bf16_t* W = (z == 0) ? Wq : (z == 1) ? Wk : Wv;
  bf16_t*       D = (z == 0) ? Q  : (z == 1) ? K  : V;
  gemm_core_async(X, W, D, nullptr, nullptr, (z == 2) ? 1 : 0);
}

__global__ __launch_bounds__(256, 2) void gemm_out_a(
    const bf16_t* __restrict__ ctx, const bf16_t* __restrict__ Wo,
    float* __restrict__ out, const float* __restrict__ bo) {
  gemm_core_async(ctx, Wo, nullptr, out, bo, 2);
}

// ---------------------------------------------------------------------------
// Flash-style causal attention, transposed-S softmax, UNIFORM blocks.
// Grid (8,16,2), 256 thr. Block x processes q-tiles {x, 15-x} sequentially:
// (x+1) + (16-x) = 17 K-tile iterations for every block. 256 blocks, 1/CU.
// Q,K: [B,H,S,64] bf16; V^T: [B,H,64,S] bf16; ctx: [B,S,1024] bf16.
// Wave w owns q-rows [w*32, w*32+32) of the current q-tile.
// S^T = MFMA(A=K, B=Q): q=l15 (col), key=ntk*16+quad*4+r.  Softmax is
// register-local + shfl_xor(16,32); alpha/lrow broadcast via __shfl.
// ---------------------------------------------------------------------------
__global__ __launch_bounds__(256, 2) void attn(
    const bf16_t* __restrict__ Qw, const bf16_t* __restrict__ Kw,
    const bf16_t* __restrict__ Vw, bf16_t* __restrict__ ctx) {
  constexpr int LDK = 72, LDV = 136, LDP = 136;
  __shared__ __align__(16) bf16_t Ks[128 * LDK];
  __shared__ __align__(16) bf16_t Vts[64 * LDV];
  __shared__ __align__(16) bf16_t Ps[128 * LDP];

  const int tid  = threadIdx.x;
  const int lane = tid & 63;
  const int w    = tid >> 6;
  const int quad = lane >> 4;
  const int l15  = lane & 15;
  const int b    = blockIdx.z;
  const int h    = blockIdx.y;
  const size_t bh = (size_t)(b * 16 + h) * (size_t)(2048 * 64);
  const bf16_t* Qh = Qw + bh;
  const bf16_t* Kh = Kw + bh;
  const bf16_t* Vh = Vw + bh;       // [64][2048]

  const int srow = tid >> 3, schk = tid & 7;
  const int vrow = tid >> 4, vchk = tid & 15;

  const float sc_log2 = 0.125f * 1.44269504088896340736f;  // 1/sqrt(64)*log2e

  for (int pass = 0; pass < 2; ++pass) {
    const int qt = (pass == 0) ? blockIdx.x : 15 - blockIdx.x;

    __syncthreads();                 // prior pass's Ps/Ks/Vts reads complete
    bf16_t* Qs = Ps;                 // stage Q through Ps region (stride LDK)
    {
      u32x4 rq[4];
#pragma unroll
      for (int s2 = 0; s2 < 4; ++s2)
        rq[s2] = *(const u32x4*)(Qh + (size_t)(qt * 128 + srow + s2 * 32) * 64 + schk * 8);
#pragma unroll
      for (int s2 = 0; s2 < 4; ++s2)
        *(u32x4*)&Qs[(srow + s2 * 32) * LDK + schk * 8] = rq[s2];
    }
    __syncthreads();
    bf16x8 qF[2][2];
#pragma unroll
    for (int kq = 0; kq < 2; ++kq)
#pragma unroll
      for (int k2 = 0; k2 < 2; ++k2)
        qF[kq][k2] = *(const bf16x8*)
            &Qs[(w * 32 + kq * 16 + l15) * LDK + k2 * 32 + quad * 8];

    f32x4 O[2][4] = {};
    float mrow[2] = {-1e30f, -1e30f};
    float lrow[2] = {0.f, 0.f};

    // --- preload kt=0 K/V tiles into registers ---
    u32x4 rk[4], rv[4];
#pragma unroll
    for (int s2 = 0; s2 < 4; ++s2)
      rk[s2] = *(const u32x4*)(Kh + (size_t)(srow + s2 * 32) * 64 + schk * 8);
#pragma unroll
    for (int s2 = 0; s2 < 4; ++s2)
      rv[s2] = *(const u32x4*)(Vh + (size_t)(vrow + s2 * 16) * 2048 + vchk * 8);

    for (int kt = 0; kt <= qt; ++kt) {
      __syncthreads();   // prior-iter LDS reads (and qF reads at kt=0) done
#pragma unroll
      for (int s2 = 0; s2 < 4; ++s2)
        *(u32x4*)&Ks[(srow + s2 * 32) * LDK + schk * 8] = rk[s2];
#pragma unroll
      for (int s2 = 0; s2 < 4; ++s2)
        *(u32x4*)&Vts[(vrow + s2 * 16) * LDV + vchk * 8] = rv[s2];
      __syncthreads();

      // --- prefetch next K/V tile (overlaps all compute below) ---
      if (kt < qt) {
        const int kn = kt + 1;
#pragma unroll
        for (int s2 = 0; s2 < 4; ++s2)
          rk[s2] = *(const u32x4*)(Kh + (size_t)(kn * 128 + srow + s2 * 32) * 64 + schk * 8);
#pragma unroll
        for (int s2 = 0; s2 < 4; ++s2)
          rv[s2] = *(const u32x4*)(Vh + (size_t)(vrow + s2 * 16) * 2048 + kn * 128 + vchk * 8);
      }

      // --- S^T = K Q^T : St[kq][ntk], q=l15 (col), key=ntk*16+quad*4+r ---
      f32x4 St[2][8] = {};
#pragma unroll
      for (int ntk = 0; ntk < 8; ++ntk) {
        const int kr = ntk * 16 + l15;           // key row for A-frag
#pragma unroll
        for (int k2 = 0; k2 < 2; ++k2) {
          const bf16x8 kF = *(const bf16x8*)&Ks[kr * LDK + k2 * 32 + quad * 8];
#pragma unroll
          for (int kq = 0; kq < 2; ++kq)
            St[kq][ntk] = MFMA16(kF, qF[kq][k2], St[kq][ntk]);
        }
      }

      // --- diag mask only on the diagonal tile (wave-uniform branch) ---
      if (kt == qt) {
#pragma unroll
        for (int kq = 0; kq < 2; ++kq) {
          const int ql = w * 32 + kq * 16 + l15;
#pragma unroll
          for (int ntk = 0; ntk < 8; ++ntk)
#pragma unroll
            for (int r = 0; r < 4; ++r)
              if (ntk * 16 + quad * 4 + r > ql) St[kq][ntk][r] = -1e30f;
        }
      }

      // --- online softmax (register-local per q-column) ---
      float aq[2];
#pragma unroll
      for (int kq = 0; kq < 2; ++kq) {
        float mx = -1e30f;
#pragma unroll
        for (int ntk = 0; ntk < 8; ++ntk)
#pragma unroll
          for (int r = 0; r < 4; ++r) mx = fmaxf(mx, St[kq][ntk][r]);
        mx = fmaxf(mx, __shfl_xor(mx, 16));
        mx = fmaxf(mx, __shfl_xor(mx, 32));
        const float mnew  = fmaxf(mrow[kq], mx);
        const float alpha = exp2f((mrow[kq] - mnew) * sc_log2);
        mrow[kq] = mnew;
        float rs = 0.f;
#pragma unroll
        for (int ntk = 0; ntk < 8; ++ntk) {
          union { uint64_t u; bf16_t h4[4]; } pk;
#pragma unroll
          for (int r = 0; r < 4; ++r) {
            const float p = exp2f((St[kq][ntk][r] - mnew) * sc_log2);
            rs += p;
            pk.h4[r] = (bf16_t)p;
          }
          *(uint64_t*)&Ps[(w * 32 + kq * 16 + l15) * LDP + ntk * 16 + quad * 4] = pk.u;
        }
        rs += __shfl_xor(rs, 16);
        rs += __shfl_xor(rs, 32);
        lrow[kq] = lrow[kq] * alpha + rs;
        aq[kq] = alpha;
      }

      // --- rescale O by alpha (broadcast to O layout q=quad*4+r) ---
#pragma unroll
      for (int mt = 0; mt < 2; ++mt) {
#pragma unroll
        for (int r = 0; r < 4; ++r) {
          const float a = __shfl(aq[mt], quad * 4 + r);
#pragma unroll
          for (int nt = 0; nt < 4; ++nt) O[mt][nt][r] *= a;
        }
      }

      // --- O += P V  (wave-private Ps rows; same-wave RAW, no barrier) ---
#pragma unroll
      for (int kk = 0; kk < 128; kk += 32) {
        const int co = kk + quad * 8;
        bf16x8 pF[2], vF[4];
#pragma unroll
        for (int mt = 0; mt < 2; ++mt)
          pF[mt] = *(const bf16x8*)&Ps[(w * 32 + mt * 16 + l15) * LDP + co];
#pragma unroll
        for (int nt = 0; nt < 4; ++nt)
          vF[nt] = *(const bf16x8*)&Vts[(nt * 16 + l15) * LDV + co];
#pragma unroll
        for (int mt = 0; mt < 2; ++mt)
#pragma unroll
          for (int nt = 0; nt < 4; ++nt)
            O[mt][nt] = MFMA16(pF[mt], vF[nt], O[mt][nt]);
      }
    }

    // --- epilogue: normalize (lrow broadcast from q-column lanes), store ---
#pragma unroll
    for (int mt = 0; mt < 2; ++mt) {
#pragma unroll
      for (int r = 0; r < 4; ++r) {
        const float lr = __shfl(lrow[mt], quad * 4 + r);
        const float iv = 1.f / lr;
        const int s = qt * 128 + w * 32 + mt * 16 + quad * 4 + r;
#pragma unroll
        for (int nt = 0; nt < 4; ++nt) {
          const int hd = nt * 16 + l15;
          ctx[(size_t)(b * 2048 + s) * 1024 + h * 64 + hd] =
              (bf16_t)(O[mt][nt][r] * iv);
        }
      }
    }
  }
}

// ---------------------------------------------------------------------------
extern "C" void kernel_launch(void* const* d_in, const int* in_sizes, int n_in,
                              void* d_out, int out_size, void* d_ws, size_t ws_size,
                              hipStream_t stream) {
  const float* x  = (const float*)d_in[0];
  const float* Wq = (const float*)d_in[1];
  const float* Wk = (const float*)d_in[2];
  const float* Wv = (const float*)d_in[3];
  const float* Wo = (const float*)d_in[4];
  const float* bo = (const float*)d_in[5];

  bf16_t* ws   = (bf16_t*)d_ws;       // ws: exactly 32 MB used
  bf16_t* Qw   = ws;                  // 4M bf16 elems each
  bf16_t* Kw   = ws + 4194304;
  bf16_t* Vw   = ws + 8388608;        // [B,H,64,S]
  bf16_t* ctxw = ws + 12582912;
  bf16_t* Wob  = Qw;                  // Q region reused after attn

  bf16_t* dscr = (bf16_t*)d_out;      // d_out as bf16 scratch (14 of 16 MB)
  bf16_t* xb   = dscr;                // 8 MB
  bf16_t* Wqb  = dscr + 4194304;      // 2 MB each
  bf16_t* Wkb  = dscr + 5242880;
  bf16_t* Wvb  = dscr + 6291456;      // ends at 14 MB
  float*  out  = (float*)d_out;       // final fp32 output overwrites scratch

  dim3 blk(256);
  cvt_all<<<dim3(4096, 4), blk, 0, stream>>>(x, Wq, Wk, Wv, xb, Wqb, Wkb, Wvb);
  gemm_qkv_a<<<dim3(8, 32, 3), blk, 0, stream>>>(xb, Wqb, Wkb, Wvb, Qw, Kw, Vw);
  attn<<<dim3(8, 16, 2), blk, 0, stream>>>(Qw, Kw, Vw, ctxw);
  cvt_one<<<dim3(1024), blk, 0, stream>>>(Wo, Wob);
  gemm_out_a<<<dim3(8, 32, 1), blk, 0, stream>>>(ctxw, Wob, out, bo);
}

// Round 9
// 188.480 us; speedup vs baseline: 1.0335x; 1.0335x over previous
//
#include <hip/hip_runtime.h>
#include <stdint.h>

// ---------------------------------------------------------------------------
// MultiHeadAttention forward, MI355X/gfx950.  Round 9.
// fp32 I/O, bf16 MFMA compute. B=2 S=2048 D=1024 H=16 HD=64. M=4096.
// R9 vs R8 (194.8 us — attn 2-pass regressed):
//  1) attn: REVERTED to R7 exactly (59.2 us). Model: per-iter cost 8.3K cyc
//     @2 blocks/CU vs 11.8K @1 block/CU — co-residency is worth 1.42x; the
//     2-pass uniform grid destroyed it. Keep (16,16,2) + z-pairing.
//  2) gemm_out: new 64x128-tile mixed-staging kernel, grid (8,64)=512 blocks
//     (2/CU overlap — R8 lesson). A=ctx bf16 via global_load_lds; B=Wo read
//     FP32 from d_in with register cvt (kills cvt_one dispatch + Wob buffer).
// Pipeline: cvt_all(x,Wq,Wk,Wv -> d_out scratch) -> gemm_qkv_a -> attn(R7)
//        -> gemm_out_m (fp32 out over d_out; reads no d_out scratch).
// MFMA mfma_f32_16x16x32_bf16 layouts [m89-verified]:
//   A-frag: lane(quad,l15) holds A[m=l15][k=quad*8+j]  (contig bf16x8)
//   B-frag: B[n=l15][k=quad*8+j];  C/D: col=l15, row=quad*4+reg
// Async staging swizzle: LDS[r][pc] = G[r][pc^(r&7)]; frag reads ck^(r&7).
// ---------------------------------------------------------------------------

typedef __bf16 bf16_t;
typedef __bf16 bf16x8 __attribute__((ext_vector_type(8)));
typedef float  f32x4  __attribute__((ext_vector_type(4)));
typedef uint32_t u32x4 __attribute__((ext_vector_type(4)));

#define MFMA16(A, B, C) __builtin_amdgcn_mfma_f32_16x16x32_bf16(A, B, C, 0, 0, 0)

__device__ __forceinline__ void async_ld16(const bf16_t* g, bf16_t* l) {
  __builtin_amdgcn_global_load_lds(
      (const __attribute__((address_space(1))) void*)g,
      (__attribute__((address_space(3))) void*)l, 16, 0, 0);
}

__device__ __forceinline__ u32x4 ld8(const float* p) {
  const float4 a = *(const float4*)p;
  const float4 b = *(const float4*)(p + 4);
  union { u32x4 v; bf16_t h[8]; } r;
  r.h[0] = (bf16_t)a.x; r.h[1] = (bf16_t)a.y;
  r.h[2] = (bf16_t)a.z; r.h[3] = (bf16_t)a.w;
  r.h[4] = (bf16_t)b.x; r.h[5] = (bf16_t)b.y;
  r.h[6] = (bf16_t)b.z; r.h[7] = (bf16_t)b.w;
  return r.v;
}

// --- fp32 -> bf16 converter: y=0 x (4096 blks); y=1..3 Wq/Wk/Wv (1024) -----
__global__ __launch_bounds__(256) void cvt_all(
    const float* __restrict__ sx, const float* __restrict__ s1,
    const float* __restrict__ s2, const float* __restrict__ s3,
    bf16_t* __restrict__ dx, bf16_t* __restrict__ d1,
    bf16_t* __restrict__ d2, bf16_t* __restrict__ d3) {
  const int y = blockIdx.y;
  if (y != 0 && blockIdx.x >= 1024) return;
  const int i4 = (blockIdx.x * 256 + threadIdx.x) * 4;
  const float* s = (y == 0) ? sx : (y == 1) ? s1 : (y == 2) ? s2 : s3;
  bf16_t*      d = (y == 0) ? dx : (y == 1) ? d1 : (y == 2) ? d2 : d3;
  const float4 v = *(const float4*)(s + i4);
  union { uint64_t u; bf16_t h[4]; } pk;
  pk.h[0] = (bf16_t)v.x; pk.h[1] = (bf16_t)v.y;
  pk.h[2] = (bf16_t)v.z; pk.h[3] = (bf16_t)v.w;
  *(uint64_t*)(d + i4) = pk.u;
}

// ---------------------------------------------------------------------------
// Async-staged bf16 GEMM (128x128, BK=64): QKV projections.
// mode 0: Q/K [B,H,S,64]; mode 1: V^T [B,H,64,S].
// ---------------------------------------------------------------------------
__global__ __launch_bounds__(256, 2) void gemm_qkv_a(
    const bf16_t* __restrict__ X,  const bf16_t* __restrict__ Wq,
    const bf16_t* __restrict__ Wk, const bf16_t* __restrict__ Wv,
    bf16_t* __restrict__ Q, bf16_t* __restrict__ K, bf16_t* __restrict__ V) {
  const int z = blockIdx.z;
  const bf16_t* W = (z == 0) ? Wq : (z == 1) ? Wk : Wv;
  bf16_t*       D = (z == 0) ? Q  : (z == 1) ? K  : V;
  const int mode = (z == 2) ? 1 : 0;

  __shared__ __align__(16) bf16_t As[128 * 64];
  __shared__ __align__(16) bf16_t Bs[128 * 64];

  const int tid  = threadIdx.x;
  const int lane = tid & 63;
  const int w    = tid >> 6;
  const int quad = lane >> 4;
  const int l15  = lane & 15;
  const int bm   = blockIdx.y * 128;
  const int bn   = blockIdx.x * 128;
  const int wm   = (w >> 1) * 64;
  const int wn   = (w & 1) * 64;
  const int sr   = lane >> 3;
  const int sc   = lane & 7;

  f32x4 acc[4][4] = {};

  for (int k0 = 0; k0 < 1024; k0 += 64) {
#pragma unroll
    for (int j = 0; j < 4; ++j) {
      const int r0 = w * 32 + j * 8;
      const int r  = r0 + sr;
      const int c  = sc ^ (r & 7);
      async_ld16(X + (size_t)(bm + r) * 1024 + k0 + c * 8, &As[r0 * 64]);
      async_ld16(W + (size_t)(bn + r) * 1024 + k0 + c * 8, &Bs[r0 * 64]);
    }
    __syncthreads();
#pragma unroll
    for (int kk = 0; kk < 64; kk += 32) {
      const int ck = (kk >> 3) + quad;
      bf16x8 aF[4], bF[4];
#pragma unroll
      for (int mt = 0; mt < 4; ++mt) {
        const int r = wm + mt * 16 + l15;
        aF[mt] = *(const bf16x8*)&As[r * 64 + (ck ^ (r & 7)) * 8];
      }
#pragma unroll
      for (int nt = 0; nt < 4; ++nt) {
        const int r = wn + nt * 16 + l15;
        bF[nt] = *(const bf16x8*)&Bs[r * 64 + (ck ^ (r & 7)) * 8];
      }
#pragma unroll
      for (int mt = 0; mt < 4; ++mt)
#pragma unroll
        for (int nt = 0; nt < 4; ++nt)
          acc[mt][nt] = MFMA16(aF[mt], bF[nt], acc[mt][nt]);
    }
    __syncthreads();
  }

#pragma unroll
  for (int mt = 0; mt < 4; ++mt) {
#pragma unroll
    for (int nt = 0; nt < 4; ++nt) {
      const int n  = bn + wn + nt * 16 + l15;
      const int mb = bm + wm + mt * 16 + quad * 4;
      const int h = n >> 6, hd = n & 63;
      if (mode == 0) {               // Q/K: [B,H,S,64]
#pragma unroll
        for (int r = 0; r < 4; ++r) {
          const int m = mb + r;
          const int b = m >> 11, s = m & 2047;
          D[(size_t)b * 2097152 + (size_t)h * 131072 + (size_t)s * 64 + hd] =
              (bf16_t)acc[mt][nt][r];
        }
      } else {                       // V^T: [B,H,64,S]; 4 consecutive tokens
        const int b = mb >> 11, s0 = mb & 2047;
        union { uint64_t u; bf16_t h4[4]; } pk;
#pragma unroll
        for (int r = 0; r < 4; ++r) pk.h4[r] = (bf16_t)acc[mt][nt][r];
        *(uint64_t*)(D + (size_t)b * 2097152 + (size_t)h * 131072 +
                     (size_t)hd * 2048 + s0) = pk.u;
      }
    }
  }
}

// ---------------------------------------------------------------------------
// gemm_out: 64x128 tile, BK=64, grid (8,64)=512 blocks (2/CU overlap).
// A = ctx bf16 (async LDS staging); B = Wo FP32 from d_in (register cvt ->
// swizzled LDS writes). out = ctx @ Wo^T + bo, FP32.
// ---------------------------------------------------------------------------
__global__ __launch_bounds__(256, 2) void gemm_out_m(
    const bf16_t* __restrict__ ctx, const float* __restrict__ Wo,
    float* __restrict__ out, const float* __restrict__ bo) {
  __shared__ __align__(16) bf16_t As[64 * 64];
  __shared__ __align__(16) bf16_t Bs[128 * 64];

  const int tid  = threadIdx.x;
  const int lane = tid & 63;
  const int w    = tid >> 6;
  const int quad = lane >> 4;
  const int l15  = lane & 15;
  const int bm   = blockIdx.y * 64;
  const int bn   = blockIdx.x * 128;
  const int wm   = (w >> 1) * 32;
  const int wn   = (w & 1) * 64;
  const int sr   = lane >> 3;
  const int sc   = lane & 7;
  const int srow = tid >> 3;        // 0..31
  const int schk = tid & 7;

  f32x4 acc[2][4] = {};

  for (int k0 = 0; k0 < 1024; k0 += 64) {
    // A: async bf16 staging (2 row-groups per wave)
#pragma unroll
    for (int j = 0; j < 2; ++j) {
      const int r0 = w * 16 + j * 8;
      const int r  = r0 + sr;
      const int c  = sc ^ (r & 7);
      async_ld16(ctx + (size_t)(bm + r) * 1024 + k0 + c * 8, &As[r0 * 64]);
    }
    // B: fp32 global -> regs (cvt) -> swizzled LDS (Bs free since loop-end barrier)
    u32x4 rb[4];
#pragma unroll
    for (int s2 = 0; s2 < 4; ++s2) {
      const int r = srow + s2 * 32;
      rb[s2] = ld8(Wo + (size_t)(bn + r) * 1024 + k0 + schk * 8);
    }
#pragma unroll
    for (int s2 = 0; s2 < 4; ++s2) {
      const int r = srow + s2 * 32;
      *(u32x4*)&Bs[r * 64 + ((schk ^ (r & 7)) * 8)] = rb[s2];
    }
    __syncthreads();    // drains async A (vmcnt) + B ds_writes (lgkmcnt)
#pragma unroll
    for (int kk = 0; kk < 64; kk += 32) {
      const int ck = (kk >> 3) + quad;
      bf16x8 aF[2], bF[4];
#pragma unroll
      for (int mt = 0; mt < 2; ++mt) {
        const int r = wm + mt * 16 + l15;
        aF[mt] = *(const bf16x8*)&As[r * 64 + (ck ^ (r & 7)) * 8];
      }
#pragma unroll
      for (int nt = 0; nt < 4; ++nt) {
        const int r = wn + nt * 16 + l15;
        bF[nt] = *(const bf16x8*)&Bs[r * 64 + (ck ^ (r & 7)) * 8];
      }
#pragma unroll
      for (int mt = 0; mt < 2; ++mt)
#pragma unroll
        for (int nt = 0; nt < 4; ++nt)
          acc[mt][nt] = MFMA16(aF[mt], bF[nt], acc[mt][nt]);
    }
    __syncthreads();    // all reads done before next staging overwrites
  }

#pragma unroll
  for (int mt = 0; mt < 2; ++mt) {
#pragma unroll
    for (int nt = 0; nt < 4; ++nt) {
      const int n  = bn + wn + nt * 16 + l15;
      const int mb = bm + wm + mt * 16 + quad * 4;
      const float bv = bo[n];
#pragma unroll
      for (int r = 0; r < 4; ++r)
        out[(size_t)(mb + r) * 1024 + n] = acc[mt][nt][r] + bv;
    }
  }
}

// ---------------------------------------------------------------------------
// Flash-style causal attention (R7, 59.2 us). Grid (16,16,2), 256 thr.
// qt remap: z==0 -> x, z==1 -> 15-x; ids differ by 256 -> same CU, 2 blocks/CU.
// Q,K: [B,H,S,64] bf16; V^T: [B,H,64,S] bf16; ctx: [B,S,1024] bf16.
// S^T = MFMA(A=K, B=Q): q=l15 (col), key=ntk*16+quad*4+r.  Softmax is
// register-local + shfl_xor(16,32); alpha/lrow broadcast via __shfl.
// ---------------------------------------------------------------------------
__global__ __launch_bounds__(256, 2) void attn(
    const bf16_t* __restrict__ Qw, const bf16_t* __restrict__ Kw,
    const bf16_t* __restrict__ Vw, bf16_t* __restrict__ ctx) {
  constexpr int LDK = 72, LDV = 136, LDP = 136;
  __shared__ __align__(16) bf16_t Ks[128 * LDK];
  __shared__ __align__(16) bf16_t Vts[64 * LDV];
  __shared__ __align__(16) bf16_t Ps[128 * LDP];

  const int tid  = threadIdx.x;
  const int lane = tid & 63;
  const int w    = tid >> 6;
  const int quad = lane >> 4;
  const int l15  = lane & 15;
  const int b    = blockIdx.z;
  const int qt   = (b == 0) ? blockIdx.x : 15 - blockIdx.x;
  const int h    = blockIdx.y;
  const size_t bh = (size_t)(b * 16 + h) * (size_t)(2048 * 64);
  const bf16_t* Qh = Qw + bh;
  const bf16_t* Kh = Kw + bh;
  const bf16_t* Vh = Vw + bh;       // [64][2048]

  const int srow = tid >> 3, schk = tid & 7;
  const int vrow = tid >> 4, vchk = tid & 15;

  bf16_t* Qs = Ps;                   // stage Q through Ps region (stride LDK)
  {
    u32x4 rq[4];
#pragma unroll
    for (int s2 = 0; s2 < 4; ++s2)
      rq[s2] = *(const u32x4*)(Qh + (size_t)(qt * 128 + srow + s2 * 32) * 64 + schk * 8);
#pragma unroll
    for (int s2 = 0; s2 < 4; ++s2)
      *(u32x4*)&Qs[(srow + s2 * 32) * LDK + schk * 8] = rq[s2];
  }
  __syncthreads();
  bf16x8 qF[2][2];
#pragma unroll
  for (int kq = 0; kq < 2; ++kq)
#pragma unroll
    for (int k2 = 0; k2 < 2; ++k2)
      qF[kq][k2] = *(const bf16x8*)
          &Qs[(w * 32 + kq * 16 + l15) * LDK + k2 * 32 + quad * 8];

  f32x4 O[2][4] = {};
  float mrow[2] = {-1e30f, -1e30f};
  float lrow[2] = {0.f, 0.f};

  const float sc_log2 = 0.125f * 1.44269504088896340736f;  // 1/sqrt(64)*log2e

  // --- preload kt=0 K/V tiles into registers ---
  u32x4 rk[4], rv[4];
#pragma unroll
  for (int s2 = 0; s2 < 4; ++s2)
    rk[s2] = *(const u32x4*)(Kh + (size_t)(srow + s2 * 32) * 64 + schk * 8);
#pragma unroll
  for (int s2 = 0; s2 < 4; ++s2)
    rv[s2] = *(const u32x4*)(Vh + (size_t)(vrow + s2 * 16) * 2048 + vchk * 8);

  for (int kt = 0; kt <= qt; ++kt) {
    __syncthreads();   // prior-iter LDS reads (and iter0 qF reads) complete
#pragma unroll
    for (int s2 = 0; s2 < 4; ++s2)
      *(u32x4*)&Ks[(srow + s2 * 32) * LDK + schk * 8] = rk[s2];
#pragma unroll
    for (int s2 = 0; s2 < 4; ++s2)
      *(u32x4*)&Vts[(vrow + s2 * 16) * LDV + vchk * 8] = rv[s2];
    __syncthreads();

    // --- prefetch next K/V tile (overlaps all compute below) ---
    if (kt < qt) {
      const int kn = kt + 1;
#pragma unroll
      for (int s2 = 0; s2 < 4; ++s2)
        rk[s2] = *(const u32x4*)(Kh + (size_t)(kn * 128 + srow + s2 * 32) * 64 + schk * 8);
#pragma unroll
      for (int s2 = 0; s2 < 4; ++s2)
        rv[s2] = *(const u32x4*)(Vh + (size_t)(vrow + s2 * 16) * 2048 + kn * 128 + vchk * 8);
    }

    // --- S^T = K Q^T : St[kq][ntk], q=l15 (col), key=ntk*16+quad*4+r ---
    f32x4 St[2][8] = {};
#pragma unroll
    for (int ntk = 0; ntk < 8; ++ntk) {
      const int kr = ntk * 16 + l15;           // key row for A-frag
#pragma unroll
      for (int k2 = 0; k2 < 2; ++k2) {
        const bf16x8 kF = *(const bf16x8*)&Ks[kr * LDK + k2 * 32 + quad * 8];
#pragma unroll
        for (int kq = 0; kq < 2; ++kq)
          St[kq][ntk] = MFMA16(kF, qF[kq][k2], St[kq][ntk]);
      }
    }

    // --- diag mask only on the diagonal tile (wave-uniform branch) ---
    if (kt == qt) {
#pragma unroll
      for (int kq = 0; kq < 2; ++kq) {
        const int ql = w * 32 + kq * 16 + l15;
#pragma unroll
        for (int ntk = 0; ntk < 8; ++ntk)
#pragma unroll
          for (int r = 0; r < 4; ++r)
            if (ntk * 16 + quad * 4 + r > ql) St[kq][ntk][r] = -1e30f;
      }
    }

    // --- online softmax (register-local per q-column) ---
    float aq[2];
#pragma unroll
    for (int kq = 0; kq < 2; ++kq) {
      float mx = -1e30f;
#pragma unroll
      for (int ntk = 0; ntk < 8; ++ntk)
#pragma unroll
        for (int r = 0; r < 4; ++r) mx = fmaxf(mx, St[kq][ntk][r]);
      mx = fmaxf(mx, __shfl_xor(mx, 16));
      mx = fmaxf(mx, __shfl_xor(mx, 32));
      const float mnew  = fmaxf(mrow[kq], mx);
      const float alpha = exp2f((mrow[kq] - mnew) * sc_log2);
      mrow[kq] = mnew;
      float rs = 0.f;
#pragma unroll
      for (int ntk = 0; ntk < 8; ++ntk) {
        union { uint64_t u; bf16_t h4[4]; } pk;
#pragma unroll
        for (int r = 0; r < 4; ++r) {
          const float p = exp2f((St[kq][ntk][r] - mnew) * sc_log2);
          rs += p;
          pk.h4[r] = (bf16_t)p;
        }
        *(uint64_t*)&Ps[(w * 32 + kq * 16 + l15) * LDP + ntk * 16 + quad * 4] = pk.u;
      }
      rs += __shfl_xor(rs, 16);
      rs += __shfl_xor(rs, 32);
      lrow[kq] = lrow[kq] * alpha + rs;
      aq[kq] = alpha;
    }

    // --- rescale O by alpha (broadcast to O layout q=quad*4+r) ---
#pragma unroll
    for (int mt = 0; mt < 2; ++mt) {
#pragma unroll
      for (int r = 0; r < 4; ++r) {
        const float a = __shfl(aq[mt], quad * 4 + r);
#pragma unroll
        for (int nt = 0; nt < 4; ++nt) O[mt][nt][r] *= a;
      }
    }

    // --- O += P V  (wave-private Ps rows; same-wave RAW, no barrier) ---
#pragma unroll
    for (int kk = 0; kk < 128; kk += 32) {
      const int co = kk + quad * 8;
      bf16x8 pF[2], vF[4];
#pragma unroll
      for (int mt = 0; mt < 2; ++mt)
        pF[mt] = *(const bf16x8*)&Ps[(w * 32 + mt * 16 + l15) * LDP + co];
#pragma unroll
      for (int nt = 0; nt < 4; ++nt)
        vF[nt] = *(const bf16x8*)&Vts[(nt * 16 + l15) * LDV + co];
#pragma unroll
      for (int mt = 0; mt < 2; ++mt)
#pragma unroll
        for (int nt = 0; nt < 4; ++nt)
          O[mt][nt] = MFMA16(pF[mt], vF[nt], O[mt][nt]);
    }
  }

  // --- epilogue: normalize (lrow broadcast from q-column lanes), store ---
#pragma unroll
  for (int mt = 0; mt < 2; ++mt) {
#pragma unroll
    for (int r = 0; r < 4; ++r) {
      const float lr = __shfl(lrow[mt], quad * 4 + r);
      const float iv = 1.f / lr;
      const int s = qt * 128 + w * 32 + mt * 16 + quad * 4 + r;
#pragma unroll
      for (int nt = 0; nt < 4; ++nt) {
        const int hd = nt * 16 + l15;
        ctx[(size_t)(b * 2048 + s) * 1024 + h * 64 + hd] =
            (bf16_t)(O[mt][nt][r] * iv);
      }
    }
  }
}

// ---------------------------------------------------------------------------
extern "C" void kernel_launch(void* const* d_in, const int* in_sizes, int n_in,
                              void* d_out, int out_size, void* d_ws, size_t ws_size,
                              hipStream_t stream) {
  const float* x  = (const float*)d_in[0];
  const float* Wq = (const float*)d_in[1];
  const float* Wk = (const float*)d_in[2];
  const float* Wv = (const float*)d_in[3];
  const float* Wo = (const float*)d_in[4];
  const float* bo = (const float*)d_in[5];

  bf16_t* ws   = (bf16_t*)d_ws;       // ws: exactly 32 MB used
  bf16_t* Qw   = ws;                  // 4M bf16 elems each
  bf16_t* Kw   = ws + 4194304;
  bf16_t* Vw   = ws + 8388608;        // [B,H,64,S]
  bf16_t* ctxw = ws + 12582912;

  bf16_t* dscr = (bf16_t*)d_out;      // d_out as bf16 scratch (14 of 16 MB)
  bf16_t* xb   = dscr;                // 8 MB
  bf16_t* Wqb  = dscr + 4194304;      // 2 MB each
  bf16_t* Wkb  = dscr + 5242880;
  bf16_t* Wvb  = dscr + 6291456;      // ends at 14 MB
  float*  out  = (float*)d_out;       // final fp32 output overwrites scratch

  dim3 blk(256);
  cvt_all<<<dim3(4096, 4), blk, 0, stream>>>(x, Wq, Wk, Wv, xb, Wqb, Wkb, Wvb);
  gemm_qkv_a<<<dim3(8, 32, 3), blk, 0, stream>>>(xb, Wqb, Wkb, Wvb, Qw, Kw, Vw);
  attn<<<dim3(16, 16, 2), blk, 0, stream>>>(Qw, Kw, Vw, ctxw);
  gemm_out_m<<<dim3(8, 64), blk, 0, stream>>>(ctxw, Wo, out, bo);
}